// Round 2
// baseline (852.538 us; speedup 1.0000x reference)
//
#include <hip/hip_runtime.h>

constexpr int NN   = 100000;
constexpr int NE   = 3200000;
constexpr int FIN  = 512;
constexpr int FH   = 16;
constexpr int FOUT = 64;

constexpr int BSZ  = 64;                      // nodes per agg block
constexpr int K    = (NN + BSZ - 1) / BSZ;    // 1563 agg blocks
constexpr int CAP  = 4096;                    // LDS staging cap (mean 2048, sigma ~45)
constexpr int NNP  = 100352;                  // padded node count (98*1024)

// zero deg[] (workspace is poisoned)
__global__ __launch_bounds__(256) void k_zero(int* __restrict__ deg) {
    int i = blockIdx.x * 256 + threadIdx.x;   // int4 granules
    if (i < NN / 4) ((int4*)deg)[i] = make_int4(0, 0, 0, 0);
}

// degree histogram via global atomics (dst column), 4 edges/thread
__global__ __launch_bounds__(256) void k_hist(const int* __restrict__ ei, int* __restrict__ deg) {
    int i = blockIdx.x * 256 + threadIdx.x;   // i < NE/4
    int4 d = ((const int4*)(ei + NE))[i];
    atomicAdd(&deg[d.x], 1);
    atomicAdd(&deg[d.y], 1);
    atomicAdd(&deg[d.z], 1);
    atomicAdd(&deg[d.w], 1);
}

// per-1024-chunk reduce of deg -> bsum[98]
__global__ __launch_bounds__(256) void k_red(const int* __restrict__ deg, int* __restrict__ bsum) {
    int b = blockIdx.x, t = threadIdx.x;
    int gi = b * 1024 + 4 * t;
    int s = 0;
    if (gi < NN) { int4 d = *(const int4*)&deg[gi]; s = d.x + d.y + d.z + d.w; }
    #pragma unroll
    for (int off = 32; off; off >>= 1) s += __shfl_down(s, off, 64);
    __shared__ int w[4];
    if ((t & 63) == 0) w[t >> 6] = s;
    __syncthreads();
    if (t == 0) bsum[b] = w[0] + w[1] + w[2] + w[3];
}

// chunk-local scan + chunk base -> row_ptr (exclusive), cur (scatter cursors), dis = rsqrt(deg+1)
__global__ __launch_bounds__(256) void k_scan3(const int* __restrict__ deg,
                                               const int* __restrict__ bsum,
                                               int* __restrict__ row_ptr,
                                               int* __restrict__ cur,
                                               float* __restrict__ dis) {
    int b = blockIdx.x, t = threadIdx.x;
    int cb = 0;
    for (int j = 0; j < b; ++j) cb += bsum[j];          // uniform -> scalar loads
    int gi = b * 1024 + 4 * t;
    int4 d = make_int4(0, 0, 0, 0);
    if (gi < NN) d = *(const int4*)&deg[gi];
    int ts = d.x + d.y + d.z + d.w;
    int lane = t & 63, wid = t >> 6;
    int ps = ts;
    #pragma unroll
    for (int off = 1; off < 64; off <<= 1) {
        int u = __shfl_up(ps, off, 64);
        if (lane >= off) ps += u;
    }
    __shared__ int wsum[4];
    if (lane == 63) wsum[wid] = ps;
    __syncthreads();
    int base = cb;
    for (int w = 0; w < wid; ++w) base += wsum[w];
    int r0 = base + ps - ts;
    if (gi < NN) {
        int r1 = r0 + d.x, r2 = r1 + d.y, r3 = r2 + d.z;
        *(int4*)&row_ptr[gi] = make_int4(r0, r1, r2, r3);
        *(int4*)&cur[gi]     = make_int4(r0, r1, r2, r3);
        *(float4*)&dis[gi]   = make_float4(rsqrtf((float)d.x + 1.f), rsqrtf((float)d.y + 1.f),
                                           rsqrtf((float)d.z + 1.f), rsqrtf((float)d.w + 1.f));
    }
    if (b == 0 && t == 0) row_ptr[NN] = NE;
}

// direct CSR scatter: rec2[atomic cursor of dst] = src (segment order nondeterministic; sum tolerance-safe)
__global__ __launch_bounds__(256) void k_scatter(const int* __restrict__ ei,
                                                 int* __restrict__ cur,
                                                 int* __restrict__ rec2) {
    int i = blockIdx.x * 256 + threadIdx.x;   // i < NE/4
    int4 s = ((const int4*)ei)[i];
    int4 d = ((const int4*)(ei + NE))[i];
    int p0 = atomicAdd(&cur[d.x], 1); rec2[p0] = s.x;
    int p1 = atomicAdd(&cur[d.y], 1); rec2[p1] = s.y;
    int p2 = atomicAdd(&cur[d.z], 1); rec2[p2] = s.z;
    int p3 = atomicAdd(&cur[d.w], 1); rec2[p3] = s.w;
}

// vp1 = dis * (x @ W1): one node per thread, x streamed from global (no LDS),
// W1 fetched via uniform index -> scalar cache broadcast.
__global__ __launch_bounds__(256) void k_gemm1(const float* __restrict__ x,
                                               const float* __restrict__ W1,
                                               const float* __restrict__ dis,
                                               float* __restrict__ vp1) {
    int node = blockIdx.x * 256 + threadIdx.x;
    int n = node < NN ? node : NN - 1;
    const float* xr = x + (size_t)n * FIN;
    float acc[FH];
    #pragma unroll
    for (int j = 0; j < FH; ++j) acc[j] = 0.f;
    for (int k0 = 0; k0 < FIN; k0 += 16) {    // one 64B line per lane per iter
        float4 xv[4];
        #pragma unroll
        for (int u = 0; u < 4; ++u) xv[u] = *(const float4*)&xr[k0 + 4 * u];
        #pragma unroll
        for (int u = 0; u < 4; ++u) {
            #pragma unroll
            for (int kk = 0; kk < 4; ++kk) {
                float xs = ((const float*)&xv[u])[kk];
                const float* wr = &W1[(k0 + 4 * u + kk) * FH];   // uniform -> s_load
                #pragma unroll
                for (int j = 0; j < FH; ++j) acc[j] += xs * wr[j];
            }
        }
    }
    if (node < NN) {
        float dv = dis[node];
        #pragma unroll
        for (int jb = 0; jb < 4; ++jb)
            *(float4*)&vp1[(size_t)node * FH + jb * 4] =
                make_float4(dv * acc[jb * 4], dv * acc[jb * 4 + 1],
                            dv * acc[jb * 4 + 2], dv * acc[jb * 4 + 3]);
    }
}

// CSR register-accumulating gather, 4 lanes/node, unroll-8 independent 64B-line gathers
__device__ __forceinline__ float4 seg_gather(const int* __restrict__ recs,   // LDS copy
                                             const int* __restrict__ gsrc,   // global fallback
                                             int a, int b, int nst,
                                             const float* __restrict__ vp, int q) {
    float4 acc = make_float4(0.f, 0.f, 0.f, 0.f);
    int blds = b < nst ? b : nst;
    int i = a;
    for (; i + 8 <= blds; i += 8) {
        int r0 = recs[i],     r1 = recs[i + 1], r2 = recs[i + 2], r3 = recs[i + 3];
        int r4 = recs[i + 4], r5 = recs[i + 5], r6 = recs[i + 6], r7 = recs[i + 7];
        float4 v0 = *(const float4*)&vp[(size_t)r0 * FH + q * 4];
        float4 v1 = *(const float4*)&vp[(size_t)r1 * FH + q * 4];
        float4 v2 = *(const float4*)&vp[(size_t)r2 * FH + q * 4];
        float4 v3 = *(const float4*)&vp[(size_t)r3 * FH + q * 4];
        float4 v4 = *(const float4*)&vp[(size_t)r4 * FH + q * 4];
        float4 v5 = *(const float4*)&vp[(size_t)r5 * FH + q * 4];
        float4 v6 = *(const float4*)&vp[(size_t)r6 * FH + q * 4];
        float4 v7 = *(const float4*)&vp[(size_t)r7 * FH + q * 4];
        acc.x += ((v0.x + v1.x) + (v2.x + v3.x)) + ((v4.x + v5.x) + (v6.x + v7.x));
        acc.y += ((v0.y + v1.y) + (v2.y + v3.y)) + ((v4.y + v5.y) + (v6.y + v7.y));
        acc.z += ((v0.z + v1.z) + (v2.z + v3.z)) + ((v4.z + v5.z) + (v6.z + v7.z));
        acc.w += ((v0.w + v1.w) + (v2.w + v3.w)) + ((v4.w + v5.w) + (v6.w + v7.w));
    }
    for (; i < blds; ++i) {
        int r0 = recs[i];
        float4 v0 = *(const float4*)&vp[(size_t)r0 * FH + q * 4];
        acc.x += v0.x; acc.y += v0.y; acc.z += v0.z; acc.w += v0.w;
    }
    for (int j = (a > nst ? a : nst); j < b; ++j) {   // overflow fallback (bucket > CAP)
        int r0 = gsrc[j];
        float4 v0 = *(const float4*)&vp[(size_t)r0 * FH + q * 4];
        acc.x += v0.x; acc.y += v0.y; acc.z += v0.z; acc.w += v0.w;
    }
    return acc;
}

// layer-1: vp2[d] = dis[d] * relu(dis[d]*(sum_s vp1[s] + vp1[d]) + b1)
__global__ __launch_bounds__(256) void k_agg1(const int* __restrict__ rec2,
                                              const int* __restrict__ row_ptr,
                                              const float* __restrict__ dis,
                                              const float* __restrict__ vp1,
                                              const float* __restrict__ b1,
                                              float* __restrict__ vp2) {
    __shared__ int recs[CAP];                 // 16 KB
    int t = threadIdx.x, k = blockIdx.x;
    int n0 = k * BSZ;
    int nend = n0 + BSZ < NN ? n0 + BSZ : NN;
    int e0 = row_ptr[n0], e1 = row_ptr[nend];
    int len = e1 - e0, nst = len < CAP ? len : CAP;
    for (int i = t; i < nst; i += 256) recs[i] = rec2[e0 + i];
    __syncthreads();                          // no barriers after: early-exit safe
    int slot = t >> 2, q = t & 3;
    int node = n0 + slot;
    if (node >= NN) return;
    int a = row_ptr[node] - e0;
    int b = row_ptr[node + 1] - e0;
    float4 acc = seg_gather(recs, rec2 + e0, a, b, nst, vp1, q);
    float dv = dis[node];
    float4 self = *(const float4*)&vp1[(size_t)node * FH + q * 4];
    float4 bb   = *(const float4*)&b1[q * 4];
    float4 o;
    o.x = dv * fmaxf(dv * (acc.x + self.x) + bb.x, 0.f);
    o.y = dv * fmaxf(dv * (acc.y + self.y) + bb.y, 0.f);
    o.z = dv * fmaxf(dv * (acc.z + self.z) + bb.z, 0.f);
    o.w = dv * fmaxf(dv * (acc.w + self.w) + bb.w, 0.f);
    *(float4*)&vp2[(size_t)node * FH + q * 4] = o;
}

// layer-2: a16 = dis[d]*(sum_s vp2[s] + vp2[d]); out = relu(a16 @ W2 + b2)
__global__ __launch_bounds__(256) void k_agg2(const int* __restrict__ rec2,
                                              const int* __restrict__ row_ptr,
                                              const float* __restrict__ dis,
                                              const float* __restrict__ vp2,
                                              const float* __restrict__ W2,
                                              const float* __restrict__ b2,
                                              float* __restrict__ out) {
    __shared__ int   recs[CAP];               // 16 KB
    __shared__ float a16[BSZ * FH];           // 4 KB
    __shared__ float ws[FH * FOUT];           // 4 KB
    int t = threadIdx.x, k = blockIdx.x;
    *(float4*)&ws[t * 4] = *(const float4*)&W2[t * 4];   // 256*4 = FH*FOUT
    int n0 = k * BSZ;
    int nend = n0 + BSZ < NN ? n0 + BSZ : NN;
    int e0 = row_ptr[n0], e1 = row_ptr[nend];
    int len = e1 - e0, nst = len < CAP ? len : CAP;
    for (int i = t; i < nst; i += 256) recs[i] = rec2[e0 + i];
    __syncthreads();
    int slot = t >> 2, q = t & 3;
    int node = n0 + slot;
    float4 r = make_float4(0.f, 0.f, 0.f, 0.f);
    if (node < NN) {
        int a = row_ptr[node] - e0;
        int b = row_ptr[node + 1] - e0;
        float4 acc = seg_gather(recs, rec2 + e0, a, b, nst, vp2, q);
        float dv = dis[node];
        float4 self = *(const float4*)&vp2[(size_t)node * FH + q * 4];
        r.x = dv * (acc.x + self.x);
        r.y = dv * (acc.y + self.y);
        r.z = dv * (acc.z + self.z);
        r.w = dv * (acc.w + self.w);
    }
    *(float4*)&a16[slot * FH + q * 4] = r;
    __syncthreads();
    int j = t & 63;
    float bj = b2[j];
    float wreg[FH];
    #pragma unroll
    for (int kk = 0; kk < FH; ++kk) wreg[kk] = ws[kk * FOUT + j];
    for (int n = t >> 6; n < BSZ; n += 4) {
        int node2 = n0 + n;
        if (node2 >= NN) break;
        const float* ar = &a16[n * FH];
        float s = 0.f;
        #pragma unroll
        for (int kk = 0; kk < FH; ++kk) s += ar[kk] * wreg[kk];
        out[(size_t)node2 * FOUT + j] = fmaxf(s + bj, 0.f);
    }
}

extern "C" void kernel_launch(void* const* d_in, const int* in_sizes, int n_in,
                              void* d_out, int out_size, void* d_ws, size_t ws_size,
                              hipStream_t stream) {
    const float* x  = (const float*)d_in[0];
    const int*   ei = (const int*)d_in[1];
    const float* W1 = (const float*)d_in[2];
    const float* b1 = (const float*)d_in[3];
    const float* W2 = (const float*)d_in[4];
    const float* b2 = (const float*)d_in[5];
    float* out = (float*)d_out;

    // workspace ~27.6 MB (all 16B-aligned word counts)
    char* p = (char*)d_ws;
    int*   deg     = (int*)p;    p += (size_t)NNP * 4;
    int*   bsum    = (int*)p;    p += 128 * 4;
    int*   row_ptr = (int*)p;    p += (size_t)(NNP + 4) * 4;
    int*   cur     = (int*)p;    p += (size_t)NNP * 4;
    float* dis     = (float*)p;  p += (size_t)NNP * 4;
    int*   rec2    = (int*)p;    p += (size_t)NE * 4;          // 12.8 MB
    float* vp1     = (float*)p;  p += (size_t)NN * FH * 4;     // 6.4 MB
    float* vp2     = (float*)p;                                // 6.4 MB

    k_zero   <<<98,   256, 0, stream>>>(deg);
    k_hist   <<<3125, 256, 0, stream>>>(ei, deg);
    k_red    <<<98,   256, 0, stream>>>(deg, bsum);
    k_scan3  <<<98,   256, 0, stream>>>(deg, bsum, row_ptr, cur, dis);
    k_scatter<<<3125, 256, 0, stream>>>(ei, cur, rec2);

    k_gemm1  <<<(NN + 255) / 256, 256, 0, stream>>>(x, W1, dis, vp1);
    k_agg1   <<<K, 256, 0, stream>>>(rec2, row_ptr, dis, vp1, b1, vp2);
    k_agg2   <<<K, 256, 0, stream>>>(rec2, row_ptr, dis, vp2, W2, b2, out);
}

// Round 3
// 551.948 us; speedup vs baseline: 1.5446x; 1.5446x over previous
//
#include <hip/hip_runtime.h>

constexpr int NN   = 100000;
constexpr int NE   = 3200000;
constexpr int FIN  = 512;
constexpr int FH   = 16;
constexpr int FOUT = 64;

constexpr int BSH = 6;                     // bucket shift (64 nodes/bucket)
constexpr int BSZ = 64;
constexpr int K   = (NN + BSZ - 1) / BSZ;  // 1563 buckets
constexpr int NB  = 512;                   // binning blocks
constexpr int CHUNK = NE / NB;             // 6250 edges per block (exact)
constexpr int CAP = 4096;                  // LDS staging cap per bucket (mean 2048, sigma ~45)

// per-block bucket counts: M[k*NB + b]
__global__ __launch_bounds__(256) void k_cnt(const int* __restrict__ ei, int* __restrict__ M) {
    __shared__ int h[K];
    int t = threadIdx.x, b = blockIdx.x;
    for (int i = t; i < K; i += 256) h[i] = 0;
    __syncthreads();
    int e0 = b * CHUNK;
    for (int e = e0 + t; e < e0 + CHUNK; e += 256)
        atomicAdd(&h[ei[NE + e] >> BSH], 1);
    __syncthreads();
    for (int i = t; i < K; i += 256) M[i * NB + b] = h[i];
}

// per bucket-row exclusive scan over the NB blocks, in place; bucket totals out.
__global__ __launch_bounds__(256) void k_scanM(int* __restrict__ M, int* __restrict__ btot) {
    int k = blockIdx.x, t = threadIdx.x;
    int2* row = (int2*)(M + (size_t)k * NB);
    int2 v = row[t];                       // 256 threads x 2 = NB
    int s = v.x + v.y;
    int lane = t & 63, wid = t >> 6;
    int ps = s;
    #pragma unroll
    for (int off = 1; off < 64; off <<= 1) {
        int u = __shfl_up(ps, off, 64);
        if (lane >= off) ps += u;
    }
    __shared__ int wsum[4];
    if (lane == 63) wsum[wid] = ps;
    __syncthreads();
    int base = 0;
    for (int w = 0; w < wid; ++w) base += wsum[w];
    int excl = base + ps - s;
    int2 o; o.x = excl; o.y = excl + v.x;
    row[t] = o;
    if (t == 255) btot[k] = excl + s;
}

// exclusive scan of bucket totals (K=1563) -> bstart[K+1]; 2 elems/thread
__global__ __launch_bounds__(1024) void k_scanB(const int* __restrict__ btot, int* __restrict__ bstart) {
    int t = threadIdx.x;
    int i0 = 2 * t, i1 = 2 * t + 1;
    int c0 = (i0 < K) ? btot[i0] : 0;
    int c1 = (i1 < K) ? btot[i1] : 0;
    int s = c0 + c1;
    int lane = t & 63, wid = t >> 6;
    int ps = s;
    #pragma unroll
    for (int off = 1; off < 64; off <<= 1) {
        int u = __shfl_up(ps, off, 64);
        if (lane >= off) ps += u;
    }
    __shared__ int wsum[16];
    if (lane == 63) wsum[wid] = ps;
    __syncthreads();
    int base = 0;
    for (int w = 0; w < wid; ++w) base += wsum[w];
    int excl = base + ps - s;
    if (i0 < K) bstart[i0] = excl;
    if (i1 < K) bstart[i1] = excl + c0;
    if (t == 0) bstart[K] = NE;
}

// deterministic scatter: rec1[pos] = (src<<6) | d_local; per-block cursors in LDS only.
// Each block's writes per bucket form a contiguous run -> L2-local, no write amplification.
__global__ __launch_bounds__(256) void k_scatter2(const int* __restrict__ ei,
                                                  const int* __restrict__ M,
                                                  const int* __restrict__ bstart,
                                                  int* __restrict__ rec) {
    __shared__ int cur[K];
    int t = threadIdx.x, b = blockIdx.x;
    for (int i = t; i < K; i += 256) cur[i] = bstart[i] + M[i * NB + b];
    __syncthreads();
    int e0 = b * CHUNK;
    for (int e = e0 + t; e < e0 + CHUNK; e += 256) {
        int s = ei[e];
        int d = ei[NE + e];
        int pos = atomicAdd(&cur[d >> BSH], 1);
        rec[pos] = (s << BSH) | (d & (BSZ - 1));
    }
}

// in-bucket counting sort by d_local -> full CSR by destination node (rec2 holds plain src).
// Also emits row_ptr[node] and dis[node] = rsqrt(deg+1).
__global__ __launch_bounds__(256) void k_sort2(const int* __restrict__ rec1,
                                               const int* __restrict__ bstart,
                                               int* __restrict__ rec2,
                                               int* __restrict__ row_ptr,
                                               float* __restrict__ dis) {
    __shared__ int h[BSZ];
    __shared__ int cur[BSZ];
    int t = threadIdx.x, k = blockIdx.x;
    if (t < BSZ) h[t] = 0;
    __syncthreads();
    int e0 = bstart[k], e1 = bstart[k + 1];
    for (int e = e0 + t; e < e1; e += 256)
        atomicAdd(&h[rec1[e] & (BSZ - 1)], 1);
    __syncthreads();
    if (t < BSZ) {                         // wave 0: exclusive scan of 64 counts
        int c = h[t];
        int ps = c;
        #pragma unroll
        for (int off = 1; off < 64; off <<= 1) {
            int u = __shfl_up(ps, off, 64);
            if (t >= off) ps += u;
        }
        int excl = ps - c;
        cur[t] = excl;
        int node = k * BSZ + t;
        if (node < NN) {
            row_ptr[node] = e0 + excl;
            dis[node] = rsqrtf((float)c + 1.0f);
        }
    }
    __syncthreads();
    for (int e = e0 + t; e < e1; e += 256) {
        int r = rec1[e];
        int pos = atomicAdd(&cur[r & (BSZ - 1)], 1);
        rec2[e0 + pos] = r >> BSH;        // plain src; scatter stays in ~8KB window: L2-local
    }
    if (k == 0 && t == 0) row_ptr[NN] = NE;
}

// vp1 = dis * (x @ W1): one node per thread, x streamed from global (each lane
// consumes its own 64B lines), W1 via uniform index -> scalar cache broadcast.
__global__ __launch_bounds__(256) void k_gemm1(const float* __restrict__ x,
                                               const float* __restrict__ W1,
                                               const float* __restrict__ dis,
                                               float* __restrict__ vp1) {
    int node = blockIdx.x * 256 + threadIdx.x;
    int n = node < NN ? node : NN - 1;
    const float* xr = x + (size_t)n * FIN;
    float acc[FH];
    #pragma unroll
    for (int j = 0; j < FH; ++j) acc[j] = 0.f;
    for (int k0 = 0; k0 < FIN; k0 += 16) {    // one 64B line per lane per iter
        float4 xv[4];
        #pragma unroll
        for (int u = 0; u < 4; ++u) xv[u] = *(const float4*)&xr[k0 + 4 * u];
        #pragma unroll
        for (int u = 0; u < 4; ++u) {
            #pragma unroll
            for (int kk = 0; kk < 4; ++kk) {
                float xs = ((const float*)&xv[u])[kk];
                const float* wr = &W1[(k0 + 4 * u + kk) * FH];   // uniform -> s_load
                #pragma unroll
                for (int j = 0; j < FH; ++j) acc[j] += xs * wr[j];
            }
        }
    }
    if (node < NN) {
        float dv = dis[node];
        #pragma unroll
        for (int jb = 0; jb < 4; ++jb)
            *(float4*)&vp1[(size_t)node * FH + jb * 4] =
                make_float4(dv * acc[jb * 4], dv * acc[jb * 4 + 1],
                            dv * acc[jb * 4 + 2], dv * acc[jb * 4 + 3]);
    }
}

// CSR register-accumulating gather, 4 lanes/node, unroll-8 independent 64B-line gathers
__device__ __forceinline__ float4 seg_gather(const int* __restrict__ recs,   // LDS copy
                                             const int* __restrict__ gsrc,   // global fallback
                                             int a, int b, int nst,
                                             const float* __restrict__ vp, int q) {
    float4 acc = make_float4(0.f, 0.f, 0.f, 0.f);
    int blds = b < nst ? b : nst;
    int i = a;
    for (; i + 8 <= blds; i += 8) {
        int r0 = recs[i],     r1 = recs[i + 1], r2 = recs[i + 2], r3 = recs[i + 3];
        int r4 = recs[i + 4], r5 = recs[i + 5], r6 = recs[i + 6], r7 = recs[i + 7];
        float4 v0 = *(const float4*)&vp[(size_t)r0 * FH + q * 4];
        float4 v1 = *(const float4*)&vp[(size_t)r1 * FH + q * 4];
        float4 v2 = *(const float4*)&vp[(size_t)r2 * FH + q * 4];
        float4 v3 = *(const float4*)&vp[(size_t)r3 * FH + q * 4];
        float4 v4 = *(const float4*)&vp[(size_t)r4 * FH + q * 4];
        float4 v5 = *(const float4*)&vp[(size_t)r5 * FH + q * 4];
        float4 v6 = *(const float4*)&vp[(size_t)r6 * FH + q * 4];
        float4 v7 = *(const float4*)&vp[(size_t)r7 * FH + q * 4];
        acc.x += ((v0.x + v1.x) + (v2.x + v3.x)) + ((v4.x + v5.x) + (v6.x + v7.x));
        acc.y += ((v0.y + v1.y) + (v2.y + v3.y)) + ((v4.y + v5.y) + (v6.y + v7.y));
        acc.z += ((v0.z + v1.z) + (v2.z + v3.z)) + ((v4.z + v5.z) + (v6.z + v7.z));
        acc.w += ((v0.w + v1.w) + (v2.w + v3.w)) + ((v4.w + v5.w) + (v6.w + v7.w));
    }
    for (; i < blds; ++i) {
        int r0 = recs[i];
        float4 v0 = *(const float4*)&vp[(size_t)r0 * FH + q * 4];
        acc.x += v0.x; acc.y += v0.y; acc.z += v0.z; acc.w += v0.w;
    }
    for (int j = (a > nst ? a : nst); j < b; ++j) {   // overflow fallback (bucket > CAP)
        int r0 = gsrc[j];
        float4 v0 = *(const float4*)&vp[(size_t)r0 * FH + q * 4];
        acc.x += v0.x; acc.y += v0.y; acc.z += v0.z; acc.w += v0.w;
    }
    return acc;
}

// layer-1: vp2[d] = dis[d] * relu(dis[d]*(sum_s vp1[s] + vp1[d]) + b1)
__global__ __launch_bounds__(256) void k_agg1(const int* __restrict__ rec2,
                                              const int* __restrict__ bstart,
                                              const int* __restrict__ row_ptr,
                                              const float* __restrict__ dis,
                                              const float* __restrict__ vp1,
                                              const float* __restrict__ b1,
                                              float* __restrict__ vp2) {
    __shared__ int recs[CAP];                 // 16 KB
    int t = threadIdx.x, k = blockIdx.x;
    int e0 = bstart[k], e1 = bstart[k + 1];
    int len = e1 - e0, nst = len < CAP ? len : CAP;
    for (int i = t; i < nst; i += 256) recs[i] = rec2[e0 + i];
    __syncthreads();                          // no barriers after: early-exit safe
    int slot = t >> 2, q = t & 3;
    int node = k * BSZ + slot;
    if (node >= NN) return;
    int a = row_ptr[node] - e0;
    int b = row_ptr[node + 1] - e0;
    float4 acc = seg_gather(recs, rec2 + e0, a, b, nst, vp1, q);
    float dv = dis[node];
    float4 self = *(const float4*)&vp1[(size_t)node * FH + q * 4];
    float4 bb   = *(const float4*)&b1[q * 4];
    float4 o;
    o.x = dv * fmaxf(dv * (acc.x + self.x) + bb.x, 0.f);
    o.y = dv * fmaxf(dv * (acc.y + self.y) + bb.y, 0.f);
    o.z = dv * fmaxf(dv * (acc.z + self.z) + bb.z, 0.f);
    o.w = dv * fmaxf(dv * (acc.w + self.w) + bb.w, 0.f);
    *(float4*)&vp2[(size_t)node * FH + q * 4] = o;
}

// layer-2: a16 = dis[d]*(sum_s vp2[s] + vp2[d]); out = relu(a16 @ W2 + b2)
__global__ __launch_bounds__(256) void k_agg2(const int* __restrict__ rec2,
                                              const int* __restrict__ bstart,
                                              const int* __restrict__ row_ptr,
                                              const float* __restrict__ dis,
                                              const float* __restrict__ vp2,
                                              const float* __restrict__ W2,
                                              const float* __restrict__ b2,
                                              float* __restrict__ out) {
    __shared__ int   recs[CAP];               // 16 KB
    __shared__ float a16[BSZ * FH];           // 4 KB
    __shared__ float ws[FH * FOUT];           // 4 KB
    int t = threadIdx.x, k = blockIdx.x;
    *(float4*)&ws[t * 4] = *(const float4*)&W2[t * 4];   // 256*4 = FH*FOUT
    int e0 = bstart[k], e1 = bstart[k + 1];
    int len = e1 - e0, nst = len < CAP ? len : CAP;
    for (int i = t; i < nst; i += 256) recs[i] = rec2[e0 + i];
    __syncthreads();
    int slot = t >> 2, q = t & 3;
    int node = k * BSZ + slot;
    float4 r = make_float4(0.f, 0.f, 0.f, 0.f);
    if (node < NN) {
        int a = row_ptr[node] - e0;
        int b = row_ptr[node + 1] - e0;
        float4 acc = seg_gather(recs, rec2 + e0, a, b, nst, vp2, q);
        float dv = dis[node];
        float4 self = *(const float4*)&vp2[(size_t)node * FH + q * 4];
        r.x = dv * (acc.x + self.x);
        r.y = dv * (acc.y + self.y);
        r.z = dv * (acc.z + self.z);
        r.w = dv * (acc.w + self.w);
    }
    *(float4*)&a16[slot * FH + q * 4] = r;
    __syncthreads();
    int j = t & 63;
    float bj = b2[j];
    float wreg[FH];
    #pragma unroll
    for (int kk = 0; kk < FH; ++kk) wreg[kk] = ws[kk * FOUT + j];
    for (int n = t >> 6; n < BSZ; n += 4) {
        int node2 = k * BSZ + n;
        if (node2 >= NN) break;
        const float* ar = &a16[n * FH];
        float s = 0.f;
        #pragma unroll
        for (int kk = 0; kk < FH; ++kk) s += ar[kk] * wreg[kk];
        out[(size_t)node2 * FOUT + j] = fmaxf(s + bj, 0.f);
    }
}

extern "C" void kernel_launch(void* const* d_in, const int* in_sizes, int n_in,
                              void* d_out, int out_size, void* d_ws, size_t ws_size,
                              hipStream_t stream) {
    const float* x  = (const float*)d_in[0];
    const int*   ei = (const int*)d_in[1];
    const float* W1 = (const float*)d_in[2];
    const float* b1 = (const float*)d_in[3];
    const float* W2 = (const float*)d_in[4];
    const float* b2 = (const float*)d_in[5];
    float* out = (float*)d_out;

    // workspace (~29.6 MB). rec1's 12.8MB is dead after k_sort2 and is reused
    // for vp1 (6.4MB) + vp2 (6.4MB): stream-ordered, no overlap hazard.
    char* p = (char*)d_ws;
    int*   M       = (int*)p;    p += (size_t)K * NB * 4;      // 3.2 MB
    int*   btot    = (int*)p;    p += 2048 * 4;
    int*   bstart  = (int*)p;    p += 2048 * 4;
    char*  bufA    = p;          p += (size_t)NE * 4;          // 12.8 MB (rec1 -> vp1+vp2)
    int*   rec2    = (int*)p;    p += (size_t)NE * 4;          // 12.8 MB
    int*   row_ptr = (int*)p;    p += 100032 * 4;              // 0.4 MB
    float* dis     = (float*)p;  p += 100032 * 4;              // 0.4 MB

    int*   rec1 = (int*)bufA;
    float* vp1  = (float*)bufA;
    float* vp2  = (float*)(bufA + (size_t)NN * FH * 4);

    k_cnt     <<<NB, 256, 0, stream>>>(ei, M);
    k_scanM   <<<K, 256, 0, stream>>>(M, btot);
    k_scanB   <<<1, 1024, 0, stream>>>(btot, bstart);
    k_scatter2<<<NB, 256, 0, stream>>>(ei, M, bstart, rec1);
    k_sort2   <<<K, 256, 0, stream>>>(rec1, bstart, rec2, row_ptr, dis);

    k_gemm1   <<<(NN + 255) / 256, 256, 0, stream>>>(x, W1, dis, vp1);
    k_agg1    <<<K, 256, 0, stream>>>(rec2, bstart, row_ptr, dis, vp1, b1, vp2);
    k_agg2    <<<K, 256, 0, stream>>>(rec2, bstart, row_ptr, dis, vp2, W2, b2, out);
}

// Round 4
// 502.431 us; speedup vs baseline: 1.6968x; 1.0986x over previous
//
#include <hip/hip_runtime.h>

constexpr int NN   = 100000;
constexpr int NE   = 3200000;
constexpr int FIN  = 512;
constexpr int FH   = 16;
constexpr int FOUT = 64;

constexpr int BSH = 6;                     // bucket shift (64 nodes/bucket)
constexpr int BSZ = 64;
constexpr int K   = (NN + BSZ - 1) / BSZ;  // 1563 buckets
constexpr int NB  = 512;                   // binning blocks
constexpr int CHUNK = NE / NB;             // 6250 edges per block (exact)
constexpr int CAP = 4096;                  // LDS staging cap per bucket (mean 2048, sigma ~45)

// per-block bucket counts: M[k*NB + b]
__global__ __launch_bounds__(256) void k_cnt(const int* __restrict__ ei, int* __restrict__ M) {
    __shared__ int h[K];
    int t = threadIdx.x, b = blockIdx.x;
    for (int i = t; i < K; i += 256) h[i] = 0;
    __syncthreads();
    int e0 = b * CHUNK;
    for (int e = e0 + t; e < e0 + CHUNK; e += 256)
        atomicAdd(&h[ei[NE + e] >> BSH], 1);
    __syncthreads();
    for (int i = t; i < K; i += 256) M[i * NB + b] = h[i];
}

// per bucket-row exclusive scan over the NB blocks, in place; bucket totals out.
__global__ __launch_bounds__(256) void k_scanM(int* __restrict__ M, int* __restrict__ btot) {
    int k = blockIdx.x, t = threadIdx.x;
    int2* row = (int2*)(M + (size_t)k * NB);
    int2 v = row[t];                       // 256 threads x 2 = NB
    int s = v.x + v.y;
    int lane = t & 63, wid = t >> 6;
    int ps = s;
    #pragma unroll
    for (int off = 1; off < 64; off <<= 1) {
        int u = __shfl_up(ps, off, 64);
        if (lane >= off) ps += u;
    }
    __shared__ int wsum[4];
    if (lane == 63) wsum[wid] = ps;
    __syncthreads();
    int base = 0;
    for (int w = 0; w < wid; ++w) base += wsum[w];
    int excl = base + ps - s;
    int2 o; o.x = excl; o.y = excl + v.x;
    row[t] = o;
    if (t == 255) btot[k] = excl + s;
}

// exclusive scan of bucket totals (K=1563) -> bstart[K+1]; 2 elems/thread
__global__ __launch_bounds__(1024) void k_scanB(const int* __restrict__ btot, int* __restrict__ bstart) {
    int t = threadIdx.x;
    int i0 = 2 * t, i1 = 2 * t + 1;
    int c0 = (i0 < K) ? btot[i0] : 0;
    int c1 = (i1 < K) ? btot[i1] : 0;
    int s = c0 + c1;
    int lane = t & 63, wid = t >> 6;
    int ps = s;
    #pragma unroll
    for (int off = 1; off < 64; off <<= 1) {
        int u = __shfl_up(ps, off, 64);
        if (lane >= off) ps += u;
    }
    __shared__ int wsum[16];
    if (lane == 63) wsum[wid] = ps;
    __syncthreads();
    int base = 0;
    for (int w = 0; w < wid; ++w) base += wsum[w];
    int excl = base + ps - s;
    if (i0 < K) bstart[i0] = excl;
    if (i1 < K) bstart[i1] = excl + c0;
    if (t == 0) bstart[K] = NE;
}

// deterministic scatter: rec1[pos] = (src<<6) | d_local; per-block cursors in LDS only.
__global__ __launch_bounds__(256) void k_scatter2(const int* __restrict__ ei,
                                                  const int* __restrict__ M,
                                                  const int* __restrict__ bstart,
                                                  int* __restrict__ rec) {
    __shared__ int cur[K];
    int t = threadIdx.x, b = blockIdx.x;
    for (int i = t; i < K; i += 256) cur[i] = bstart[i] + M[i * NB + b];
    __syncthreads();
    int e0 = b * CHUNK;
    for (int e = e0 + t; e < e0 + CHUNK; e += 256) {
        int s = ei[e];
        int d = ei[NE + e];
        int pos = atomicAdd(&cur[d >> BSH], 1);
        rec[pos] = (s << BSH) | (d & (BSZ - 1));
    }
}

// in-bucket counting sort by d_local -> full CSR by destination node (rec2 holds plain src).
__global__ __launch_bounds__(256) void k_sort2(const int* __restrict__ rec1,
                                               const int* __restrict__ bstart,
                                               int* __restrict__ rec2,
                                               int* __restrict__ row_ptr,
                                               float* __restrict__ dis) {
    __shared__ int h[BSZ];
    __shared__ int cur[BSZ];
    int t = threadIdx.x, k = blockIdx.x;
    if (t < BSZ) h[t] = 0;
    __syncthreads();
    int e0 = bstart[k], e1 = bstart[k + 1];
    for (int e = e0 + t; e < e1; e += 256)
        atomicAdd(&h[rec1[e] & (BSZ - 1)], 1);
    __syncthreads();
    if (t < BSZ) {                         // wave 0: exclusive scan of 64 counts
        int c = h[t];
        int ps = c;
        #pragma unroll
        for (int off = 1; off < 64; off <<= 1) {
            int u = __shfl_up(ps, off, 64);
            if (t >= off) ps += u;
        }
        int excl = ps - c;
        cur[t] = excl;
        int node = k * BSZ + t;
        if (node < NN) {
            row_ptr[node] = e0 + excl;
            dis[node] = rsqrtf((float)c + 1.0f);
        }
    }
    __syncthreads();
    for (int e = e0 + t; e < e1; e += 256) {
        int r = rec1[e];
        int pos = atomicAdd(&cur[r & (BSZ - 1)], 1);
        rec2[e0 + pos] = r >> BSH;        // plain src; scatter stays in ~8KB window: L2-local
    }
    if (k == 0 && t == 0) row_ptr[NN] = NE;
}

// consume one 64B x-line (16 k values) against 16 LDS W-rows (broadcast reads)
__device__ __forceinline__ void cons16(float acc[FH], float4 a0, float4 a1, float4 a2, float4 a3,
                                       const float* __restrict__ wrow) {
    float xs[16] = {a0.x, a0.y, a0.z, a0.w, a1.x, a1.y, a1.z, a1.w,
                    a2.x, a2.y, a2.z, a2.w, a3.x, a3.y, a3.z, a3.w};
    #pragma unroll
    for (int c = 0; c < 16; ++c) {
        float xv = xs[c];
        const float* w = &wrow[c * FH];
        #pragma unroll
        for (int jb = 0; jb < 4; ++jb) {
            float4 wv = *(const float4*)&w[jb * 4];
            acc[jb * 4 + 0] += xv * wv.x;
            acc[jb * 4 + 1] += xv * wv.y;
            acc[jb * 4 + 2] += xv * wv.z;
            acc[jb * 4 + 3] += xv * wv.w;
        }
    }
}

// vp1 = dis * (x @ W1): one node per thread; x streamed as whole 64B lines per lane
// with a hand-written depth-2 pipeline (named register sets); W1 in LDS, broadcast
// ds_read_b128 (k is wave-uniform -> same-address broadcast, conflict-free).
__global__ __launch_bounds__(256) void k_gemm1(const float* __restrict__ x,
                                               const float* __restrict__ W1,
                                               const float* __restrict__ dis,
                                               float* __restrict__ vp1) {
    __shared__ float ws[FIN * FH];        // 32 KB
    int t = threadIdx.x;
    #pragma unroll
    for (int i = 0; i < 8; ++i)
        *(float4*)&ws[i * 1024 + t * 4] = *(const float4*)&W1[i * 1024 + t * 4];
    int node = blockIdx.x * 256 + t;
    int n = node < NN ? node : NN - 1;
    const float* xr = x + (size_t)n * FIN;
    float acc[FH];
    #pragma unroll
    for (int j = 0; j < FH; ++j) acc[j] = 0.f;
    // prime 2 lines
    float4 A0 = *(const float4*)&xr[0],  A1 = *(const float4*)&xr[4],
           A2 = *(const float4*)&xr[8],  A3 = *(const float4*)&xr[12];
    float4 B0 = *(const float4*)&xr[16], B1 = *(const float4*)&xr[20],
           B2 = *(const float4*)&xr[24], B3 = *(const float4*)&xr[28];
    __syncthreads();
    #pragma unroll 1
    for (int k0 = 0; k0 + 48 <= FIN; k0 += 32) {
        float4 C0 = *(const float4*)&xr[k0 + 32], C1 = *(const float4*)&xr[k0 + 36],
               C2 = *(const float4*)&xr[k0 + 40], C3 = *(const float4*)&xr[k0 + 44];
        cons16(acc, A0, A1, A2, A3, &ws[k0 * FH]);
        A0 = C0; A1 = C1; A2 = C2; A3 = C3;
        float4 D0 = *(const float4*)&xr[k0 + 48], D1 = *(const float4*)&xr[k0 + 52],
               D2 = *(const float4*)&xr[k0 + 56], D3 = *(const float4*)&xr[k0 + 60];
        cons16(acc, B0, B1, B2, B3, &ws[(k0 + 16) * FH]);
        B0 = D0; B1 = D1; B2 = D2; B3 = D3;
    }
    cons16(acc, A0, A1, A2, A3, &ws[(FIN - 32) * FH]);
    cons16(acc, B0, B1, B2, B3, &ws[(FIN - 16) * FH]);
    if (node < NN) {
        float dv = dis[node];
        #pragma unroll
        for (int jb = 0; jb < 4; ++jb)
            *(float4*)&vp1[(size_t)node * FH + jb * 4] =
                make_float4(dv * acc[jb * 4], dv * acc[jb * 4 + 1],
                            dv * acc[jb * 4 + 2], dv * acc[jb * 4 + 3]);
    }
}

// CSR register-accumulating gather, 4 lanes/node, unroll-8 independent 64B-line gathers
__device__ __forceinline__ float4 seg_gather(const int* __restrict__ recs,   // LDS copy
                                             const int* __restrict__ gsrc,   // global fallback
                                             int a, int b, int nst,
                                             const float* __restrict__ vp, int q) {
    float4 acc = make_float4(0.f, 0.f, 0.f, 0.f);
    int blds = b < nst ? b : nst;
    int i = a;
    for (; i + 8 <= blds; i += 8) {
        int r0 = recs[i],     r1 = recs[i + 1], r2 = recs[i + 2], r3 = recs[i + 3];
        int r4 = recs[i + 4], r5 = recs[i + 5], r6 = recs[i + 6], r7 = recs[i + 7];
        float4 v0 = *(const float4*)&vp[(size_t)r0 * FH + q * 4];
        float4 v1 = *(const float4*)&vp[(size_t)r1 * FH + q * 4];
        float4 v2 = *(const float4*)&vp[(size_t)r2 * FH + q * 4];
        float4 v3 = *(const float4*)&vp[(size_t)r3 * FH + q * 4];
        float4 v4 = *(const float4*)&vp[(size_t)r4 * FH + q * 4];
        float4 v5 = *(const float4*)&vp[(size_t)r5 * FH + q * 4];
        float4 v6 = *(const float4*)&vp[(size_t)r6 * FH + q * 4];
        float4 v7 = *(const float4*)&vp[(size_t)r7 * FH + q * 4];
        acc.x += ((v0.x + v1.x) + (v2.x + v3.x)) + ((v4.x + v5.x) + (v6.x + v7.x));
        acc.y += ((v0.y + v1.y) + (v2.y + v3.y)) + ((v4.y + v5.y) + (v6.y + v7.y));
        acc.z += ((v0.z + v1.z) + (v2.z + v3.z)) + ((v4.z + v5.z) + (v6.z + v7.z));
        acc.w += ((v0.w + v1.w) + (v2.w + v3.w)) + ((v4.w + v5.w) + (v6.w + v7.w));
    }
    for (; i < blds; ++i) {
        int r0 = recs[i];
        float4 v0 = *(const float4*)&vp[(size_t)r0 * FH + q * 4];
        acc.x += v0.x; acc.y += v0.y; acc.z += v0.z; acc.w += v0.w;
    }
    for (int j = (a > nst ? a : nst); j < b; ++j) {   // overflow fallback (bucket > CAP)
        int r0 = gsrc[j];
        float4 v0 = *(const float4*)&vp[(size_t)r0 * FH + q * 4];
        acc.x += v0.x; acc.y += v0.y; acc.z += v0.z; acc.w += v0.w;
    }
    return acc;
}

// layer-1: vp2[d] = dis[d] * relu(dis[d]*(sum_s vp1[s] + vp1[d]) + b1)
__global__ __launch_bounds__(256) void k_agg1(const int* __restrict__ rec2,
                                              const int* __restrict__ bstart,
                                              const int* __restrict__ row_ptr,
                                              const float* __restrict__ dis,
                                              const float* __restrict__ vp1,
                                              const float* __restrict__ b1,
                                              float* __restrict__ vp2) {
    __shared__ int recs[CAP];                 // 16 KB
    int t = threadIdx.x, k = blockIdx.x;
    int e0 = bstart[k], e1 = bstart[k + 1];
    int len = e1 - e0, nst = len < CAP ? len : CAP;
    for (int i = t; i < nst; i += 256) recs[i] = rec2[e0 + i];
    __syncthreads();                          // no barriers after: early-exit safe
    int slot = t >> 2, q = t & 3;
    int node = k * BSZ + slot;
    if (node >= NN) return;
    int a = row_ptr[node] - e0;
    int b = row_ptr[node + 1] - e0;
    float4 acc = seg_gather(recs, rec2 + e0, a, b, nst, vp1, q);
    float dv = dis[node];
    float4 self = *(const float4*)&vp1[(size_t)node * FH + q * 4];
    float4 bb   = *(const float4*)&b1[q * 4];
    float4 o;
    o.x = dv * fmaxf(dv * (acc.x + self.x) + bb.x, 0.f);
    o.y = dv * fmaxf(dv * (acc.y + self.y) + bb.y, 0.f);
    o.z = dv * fmaxf(dv * (acc.z + self.z) + bb.z, 0.f);
    o.w = dv * fmaxf(dv * (acc.w + self.w) + bb.w, 0.f);
    *(float4*)&vp2[(size_t)node * FH + q * 4] = o;
}

// layer-2: a16 = dis[d]*(sum_s vp2[s] + vp2[d]); out = relu(a16 @ W2 + b2)
__global__ __launch_bounds__(256) void k_agg2(const int* __restrict__ rec2,
                                              const int* __restrict__ bstart,
                                              const int* __restrict__ row_ptr,
                                              const float* __restrict__ dis,
                                              const float* __restrict__ vp2,
                                              const float* __restrict__ W2,
                                              const float* __restrict__ b2,
                                              float* __restrict__ out) {
    __shared__ int   recs[CAP];               // 16 KB
    __shared__ float a16[BSZ * FH];           // 4 KB
    __shared__ float ws[FH * FOUT];           // 4 KB
    int t = threadIdx.x, k = blockIdx.x;
    *(float4*)&ws[t * 4] = *(const float4*)&W2[t * 4];   // 256*4 = FH*FOUT
    int e0 = bstart[k], e1 = bstart[k + 1];
    int len = e1 - e0, nst = len < CAP ? len : CAP;
    for (int i = t; i < nst; i += 256) recs[i] = rec2[e0 + i];
    __syncthreads();
    int slot = t >> 2, q = t & 3;
    int node = k * BSZ + slot;
    float4 r = make_float4(0.f, 0.f, 0.f, 0.f);
    if (node < NN) {
        int a = row_ptr[node] - e0;
        int b = row_ptr[node + 1] - e0;
        float4 acc = seg_gather(recs, rec2 + e0, a, b, nst, vp2, q);
        float dv = dis[node];
        float4 self = *(const float4*)&vp2[(size_t)node * FH + q * 4];
        r.x = dv * (acc.x + self.x);
        r.y = dv * (acc.y + self.y);
        r.z = dv * (acc.z + self.z);
        r.w = dv * (acc.w + self.w);
    }
    *(float4*)&a16[slot * FH + q * 4] = r;
    __syncthreads();
    int j = t & 63;
    float bj = b2[j];
    float wreg[FH];
    #pragma unroll
    for (int kk = 0; kk < FH; ++kk) wreg[kk] = ws[kk * FOUT + j];
    for (int n = t >> 6; n < BSZ; n += 4) {
        int node2 = k * BSZ + n;
        if (node2 >= NN) break;
        const float* ar = &a16[n * FH];
        float s = 0.f;
        #pragma unroll
        for (int kk = 0; kk < FH; ++kk) s += ar[kk] * wreg[kk];
        out[(size_t)node2 * FOUT + j] = fmaxf(s + bj, 0.f);
    }
}

extern "C" void kernel_launch(void* const* d_in, const int* in_sizes, int n_in,
                              void* d_out, int out_size, void* d_ws, size_t ws_size,
                              hipStream_t stream) {
    const float* x  = (const float*)d_in[0];
    const int*   ei = (const int*)d_in[1];
    const float* W1 = (const float*)d_in[2];
    const float* b1 = (const float*)d_in[3];
    const float* W2 = (const float*)d_in[4];
    const float* b2 = (const float*)d_in[5];
    float* out = (float*)d_out;

    // workspace (~29.6 MB). rec1's 12.8MB is dead after k_sort2 and is reused
    // for vp1 (6.4MB) + vp2 (6.4MB): stream-ordered, no overlap hazard.
    char* p = (char*)d_ws;
    int*   M       = (int*)p;    p += (size_t)K * NB * 4;      // 3.2 MB
    int*   btot    = (int*)p;    p += 2048 * 4;
    int*   bstart  = (int*)p;    p += 2048 * 4;
    char*  bufA    = p;          p += (size_t)NE * 4;          // 12.8 MB (rec1 -> vp1+vp2)
    int*   rec2    = (int*)p;    p += (size_t)NE * 4;          // 12.8 MB
    int*   row_ptr = (int*)p;    p += 100032 * 4;              // 0.4 MB
    float* dis     = (float*)p;  p += 100032 * 4;              // 0.4 MB

    int*   rec1 = (int*)bufA;
    float* vp1  = (float*)bufA;
    float* vp2  = (float*)(bufA + (size_t)NN * FH * 4);

    k_cnt     <<<NB, 256, 0, stream>>>(ei, M);
    k_scanM   <<<K, 256, 0, stream>>>(M, btot);
    k_scanB   <<<1, 1024, 0, stream>>>(btot, bstart);
    k_scatter2<<<NB, 256, 0, stream>>>(ei, M, bstart, rec1);
    k_sort2   <<<K, 256, 0, stream>>>(rec1, bstart, rec2, row_ptr, dis);

    k_gemm1   <<<(NN + 255) / 256, 256, 0, stream>>>(x, W1, dis, vp1);
    k_agg1    <<<K, 256, 0, stream>>>(rec2, bstart, row_ptr, dis, vp1, b1, vp2);
    k_agg2    <<<K, 256, 0, stream>>>(rec2, bstart, row_ptr, dis, vp2, W2, b2, out);
}

// Round 6
// 480.958 us; speedup vs baseline: 1.7726x; 1.0446x over previous
//
#include <hip/hip_runtime.h>

constexpr int NN   = 100000;
constexpr int NE   = 3200000;
constexpr int FIN  = 512;
constexpr int FH   = 16;
constexpr int FOUT = 64;

constexpr int BSH = 6;                     // bucket shift (64 nodes/bucket)
constexpr int BSZ = 64;
constexpr int K   = (NN + BSZ - 1) / BSZ;  // 1563 buckets
constexpr int NB  = 512;                   // binning blocks
constexpr int CHUNK = NE / NB;             // 6250 edges per block (exact)
constexpr int CAP = 4096;                  // LDS staging cap per bucket (mean 2048, sigma ~45)

constexpr int G1B = 1024;                  // gemm1 grid: 4 blocks/CU exactly
constexpr int G1T = 128;                   // gemm1 threads/block (2 waves)
constexpr int NPB = 98;                    // nodes per gemm1 block (1024*98 = 100352)

// per-block bucket counts: M[k*NB + b]
__global__ __launch_bounds__(256) void k_cnt(const int* __restrict__ ei, int* __restrict__ M) {
    __shared__ int h[K];
    int t = threadIdx.x, b = blockIdx.x;
    for (int i = t; i < K; i += 256) h[i] = 0;
    __syncthreads();
    int e0 = b * CHUNK;
    for (int e = e0 + t; e < e0 + CHUNK; e += 256)
        atomicAdd(&h[ei[NE + e] >> BSH], 1);
    __syncthreads();
    for (int i = t; i < K; i += 256) M[i * NB + b] = h[i];
}

// per bucket-row exclusive scan over the NB blocks, in place; bucket totals out.
__global__ __launch_bounds__(256) void k_scanM(int* __restrict__ M, int* __restrict__ btot) {
    int k = blockIdx.x, t = threadIdx.x;
    int2* row = (int2*)(M + (size_t)k * NB);
    int2 v = row[t];                       // 256 threads x 2 = NB
    int s = v.x + v.y;
    int lane = t & 63, wid = t >> 6;
    int ps = s;
    #pragma unroll
    for (int off = 1; off < 64; off <<= 1) {
        int u = __shfl_up(ps, off, 64);
        if (lane >= off) ps += u;
    }
    __shared__ int wsum[4];
    if (lane == 63) wsum[wid] = ps;
    __syncthreads();
    int base = 0;
    for (int w = 0; w < wid; ++w) base += wsum[w];
    int excl = base + ps - s;
    int2 o; o.x = excl; o.y = excl + v.x;
    row[t] = o;
    if (t == 255) btot[k] = excl + s;
}

// exclusive scan of bucket totals (K=1563) -> bstart[K+1]; 2 elems/thread
__global__ __launch_bounds__(1024) void k_scanB(const int* __restrict__ btot, int* __restrict__ bstart) {
    int t = threadIdx.x;
    int i0 = 2 * t, i1 = 2 * t + 1;
    int c0 = (i0 < K) ? btot[i0] : 0;
    int c1 = (i1 < K) ? btot[i1] : 0;
    int s = c0 + c1;
    int lane = t & 63, wid = t >> 6;
    int ps = s;
    #pragma unroll
    for (int off = 1; off < 64; off <<= 1) {
        int u = __shfl_up(ps, off, 64);
        if (lane >= off) ps += u;
    }
    __shared__ int wsum[16];
    if (lane == 63) wsum[wid] = ps;
    __syncthreads();
    int base = 0;
    for (int w = 0; w < wid; ++w) base += wsum[w];
    int excl = base + ps - s;
    if (i0 < K) bstart[i0] = excl;
    if (i1 < K) bstart[i1] = excl + c0;
    if (t == 0) bstart[K] = NE;
}

// deterministic scatter: rec1[pos] = (src<<6) | d_local; per-block cursors in LDS only.
__global__ __launch_bounds__(256) void k_scatter2(const int* __restrict__ ei,
                                                  const int* __restrict__ M,
                                                  const int* __restrict__ bstart,
                                                  int* __restrict__ rec) {
    __shared__ int cur[K];
    int t = threadIdx.x, b = blockIdx.x;
    for (int i = t; i < K; i += 256) cur[i] = bstart[i] + M[i * NB + b];
    __syncthreads();
    int e0 = b * CHUNK;
    for (int e = e0 + t; e < e0 + CHUNK; e += 256) {
        int s = ei[e];
        int d = ei[NE + e];
        int pos = atomicAdd(&cur[d >> BSH], 1);
        rec[pos] = (s << BSH) | (d & (BSZ - 1));
    }
}

// in-bucket counting sort by d_local -> full CSR by destination node (rec2 holds plain src).
__global__ __launch_bounds__(256) void k_sort2(const int* __restrict__ rec1,
                                               const int* __restrict__ bstart,
                                               int* __restrict__ rec2,
                                               int* __restrict__ row_ptr,
                                               float* __restrict__ dis) {
    __shared__ int h[BSZ];
    __shared__ int cur[BSZ];
    int t = threadIdx.x, k = blockIdx.x;
    if (t < BSZ) h[t] = 0;
    __syncthreads();
    int e0 = bstart[k], e1 = bstart[k + 1];
    for (int e = e0 + t; e < e1; e += 256)
        atomicAdd(&h[rec1[e] & (BSZ - 1)], 1);
    __syncthreads();
    if (t < BSZ) {                         // wave 0: exclusive scan of 64 counts
        int c = h[t];
        int ps = c;
        #pragma unroll
        for (int off = 1; off < 64; off <<= 1) {
            int u = __shfl_up(ps, off, 64);
            if (t >= off) ps += u;
        }
        int excl = ps - c;
        cur[t] = excl;
        int node = k * BSZ + t;
        if (node < NN) {
            row_ptr[node] = e0 + excl;
            dis[node] = rsqrtf((float)c + 1.0f);
        }
    }
    __syncthreads();
    for (int e = e0 + t; e < e1; e += 256) {
        int r = rec1[e];
        int pos = atomicAdd(&cur[r & (BSZ - 1)], 1);
        rec2[e0 + pos] = r >> BSH;        // plain src; scatter stays in ~8KB window: L2-local
    }
    if (k == 0 && t == 0) row_ptr[NN] = NE;
}

// consume one 64B x-line (16 k values) against 16 LDS W-rows (broadcast reads)
__device__ __forceinline__ void cons16(float acc[FH], float4 a0, float4 a1, float4 a2, float4 a3,
                                       const float* __restrict__ wrow) {
    float xs[16] = {a0.x, a0.y, a0.z, a0.w, a1.x, a1.y, a1.z, a1.w,
                    a2.x, a2.y, a2.z, a2.w, a3.x, a3.y, a3.z, a3.w};
    #pragma unroll
    for (int c = 0; c < 16; ++c) {
        float xv = xs[c];
        const float* w = &wrow[c * FH];
        #pragma unroll
        for (int jb = 0; jb < 4; ++jb) {
            float4 wv = *(const float4*)&w[jb * 4];
            acc[jb * 4 + 0] += xv * wv.x;
            acc[jb * 4 + 1] += xv * wv.y;
            acc[jb * 4 + 2] += xv * wv.z;
            acc[jb * 4 + 3] += xv * wv.w;
        }
    }
}

// vp1 = dis * (x @ W1): one node per thread; x streamed as whole 64B lines per lane
// with a depth-2 pipeline (named register sets); W1 in LDS, broadcast ds_read_b128.
// Grid 1024 x 128: exactly 4 blocks/CU (perfect balance), 2 waves/SIMD.
__global__ __launch_bounds__(G1T) void k_gemm1(const float* __restrict__ x,
                                               const float* __restrict__ W1,
                                               const float* __restrict__ dis,
                                               float* __restrict__ vp1) {
    __shared__ float ws[FIN * FH];        // 32 KB
    int t = threadIdx.x;
    #pragma unroll
    for (int i = 0; i < 16; ++i)          // 16 * 128 * 4 = 8192 floats
        *(float4*)&ws[i * 512 + t * 4] = *(const float4*)&W1[i * 512 + t * 4];
    int node = blockIdx.x * NPB + t;      // t in [0,128); only t < NPB are live
    bool live = (t < NPB) && (node < NN);
    int n = live ? node : NN - 1;
    const float* xr = x + (size_t)n * FIN;
    float acc[FH];
    #pragma unroll
    for (int j = 0; j < FH; ++j) acc[j] = 0.f;
    // prime 2 lines
    float4 A0 = *(const float4*)&xr[0],  A1 = *(const float4*)&xr[4],
           A2 = *(const float4*)&xr[8],  A3 = *(const float4*)&xr[12];
    float4 B0 = *(const float4*)&xr[16], B1 = *(const float4*)&xr[20],
           B2 = *(const float4*)&xr[24], B3 = *(const float4*)&xr[28];
    __syncthreads();
    #pragma unroll 1
    for (int k0 = 0; k0 + 48 <= FIN; k0 += 32) {
        float4 C0 = *(const float4*)&xr[k0 + 32], C1 = *(const float4*)&xr[k0 + 36],
               C2 = *(const float4*)&xr[k0 + 40], C3 = *(const float4*)&xr[k0 + 44];
        cons16(acc, A0, A1, A2, A3, &ws[k0 * FH]);
        A0 = C0; A1 = C1; A2 = C2; A3 = C3;
        float4 D0 = *(const float4*)&xr[k0 + 48], D1 = *(const float4*)&xr[k0 + 52],
               D2 = *(const float4*)&xr[k0 + 56], D3 = *(const float4*)&xr[k0 + 60];
        cons16(acc, B0, B1, B2, B3, &ws[(k0 + 16) * FH]);
        B0 = D0; B1 = D1; B2 = D2; B3 = D3;
    }
    cons16(acc, A0, A1, A2, A3, &ws[(FIN - 32) * FH]);
    cons16(acc, B0, B1, B2, B3, &ws[(FIN - 16) * FH]);
    if (live) {
        float dv = dis[node];
        #pragma unroll
        for (int jb = 0; jb < 4; ++jb)
            *(float4*)&vp1[(size_t)node * FH + jb * 4] =
                make_float4(dv * acc[jb * 4], dv * acc[jb * 4 + 1],
                            dv * acc[jb * 4 + 2], dv * acc[jb * 4 + 3]);
    }
}

// CSR register-accumulating gather, 4 lanes/node, unroll-8 independent 64B-line gathers
__device__ __forceinline__ float4 seg_gather(const int* __restrict__ recs,   // LDS copy
                                             const int* __restrict__ gsrc,   // global fallback
                                             int a, int b, int nst,
                                             const float* __restrict__ vp, int q) {
    float4 acc = make_float4(0.f, 0.f, 0.f, 0.f);
    int blds = b < nst ? b : nst;
    int i = a;
    for (; i + 8 <= blds; i += 8) {
        int r0 = recs[i],     r1 = recs[i + 1], r2 = recs[i + 2], r3 = recs[i + 3];
        int r4 = recs[i + 4], r5 = recs[i + 5], r6 = recs[i + 6], r7 = recs[i + 7];
        float4 v0 = *(const float4*)&vp[(size_t)r0 * FH + q * 4];
        float4 v1 = *(const float4*)&vp[(size_t)r1 * FH + q * 4];
        float4 v2 = *(const float4*)&vp[(size_t)r2 * FH + q * 4];
        float4 v3 = *(const float4*)&vp[(size_t)r3 * FH + q * 4];
        float4 v4 = *(const float4*)&vp[(size_t)r4 * FH + q * 4];
        float4 v5 = *(const float4*)&vp[(size_t)r5 * FH + q * 4];
        float4 v6 = *(const float4*)&vp[(size_t)r6 * FH + q * 4];
        float4 v7 = *(const float4*)&vp[(size_t)r7 * FH + q * 4];
        acc.x += ((v0.x + v1.x) + (v2.x + v3.x)) + ((v4.x + v5.x) + (v6.x + v7.x));
        acc.y += ((v0.y + v1.y) + (v2.y + v3.y)) + ((v4.y + v5.y) + (v6.y + v7.y));
        acc.z += ((v0.z + v1.z) + (v2.z + v3.z)) + ((v4.z + v5.z) + (v6.z + v7.z));
        acc.w += ((v0.w + v1.w) + (v2.w + v3.w)) + ((v4.w + v5.w) + (v6.w + v7.w));
    }
    for (; i < blds; ++i) {
        int r0 = recs[i];
        float4 v0 = *(const float4*)&vp[(size_t)r0 * FH + q * 4];
        acc.x += v0.x; acc.y += v0.y; acc.z += v0.z; acc.w += v0.w;
    }
    for (int j = (a > nst ? a : nst); j < b; ++j) {   // overflow fallback (bucket > CAP)
        int r0 = gsrc[j];
        float4 v0 = *(const float4*)&vp[(size_t)r0 * FH + q * 4];
        acc.x += v0.x; acc.y += v0.y; acc.z += v0.z; acc.w += v0.w;
    }
    return acc;
}

// layer-1: vp2[d] = dis[d] * relu(dis[d]*(sum_s vp1[s] + vp1[d]) + b1)
__global__ __launch_bounds__(256) void k_agg1(const int* __restrict__ rec2,
                                              const int* __restrict__ bstart,
                                              const int* __restrict__ row_ptr,
                                              const float* __restrict__ dis,
                                              const float* __restrict__ vp1,
                                              const float* __restrict__ b1,
                                              float* __restrict__ vp2) {
    __shared__ int recs[CAP];                 // 16 KB
    int t = threadIdx.x, k = blockIdx.x;
    int e0 = bstart[k], e1 = bstart[k + 1];
    int len = e1 - e0, nst = len < CAP ? len : CAP;
    for (int i = t; i < nst; i += 256) recs[i] = rec2[e0 + i];
    __syncthreads();                          // no barriers after: early-exit safe
    int slot = t >> 2, q = t & 3;
    int node = k * BSZ + slot;
    if (node >= NN) return;
    int a = row_ptr[node] - e0;
    int b = row_ptr[node + 1] - e0;
    float4 acc = seg_gather(recs, rec2 + e0, a, b, nst, vp1, q);
    float dv = dis[node];
    float4 self = *(const float4*)&vp1[(size_t)node * FH + q * 4];
    float4 bb   = *(const float4*)&b1[q * 4];
    float4 o;
    o.x = dv * fmaxf(dv * (acc.x + self.x) + bb.x, 0.f);
    o.y = dv * fmaxf(dv * (acc.y + self.y) + bb.y, 0.f);
    o.z = dv * fmaxf(dv * (acc.z + self.z) + bb.z, 0.f);
    o.w = dv * fmaxf(dv * (acc.w + self.w) + bb.w, 0.f);
    *(float4*)&vp2[(size_t)node * FH + q * 4] = o;
}

// layer-2: a16 = dis[d]*(sum_s vp2[s] + vp2[d]); out = relu(a16 @ W2 + b2)
__global__ __launch_bounds__(256) void k_agg2(const int* __restrict__ rec2,
                                              const int* __restrict__ bstart,
                                              const int* __restrict__ row_ptr,
                                              const float* __restrict__ dis,
                                              const float* __restrict__ vp2,
                                              const float* __restrict__ W2,
                                              const float* __restrict__ b2,
                                              float* __restrict__ out) {
    __shared__ int   recs[CAP];               // 16 KB
    __shared__ float a16[BSZ * FH];           // 4 KB
    __shared__ float ws[FH * FOUT];           // 4 KB
    int t = threadIdx.x, k = blockIdx.x;
    *(float4*)&ws[t * 4] = *(const float4*)&W2[t * 4];   // 256*4 = FH*FOUT
    int e0 = bstart[k], e1 = bstart[k + 1];
    int len = e1 - e0, nst = len < CAP ? len : CAP;
    for (int i = t; i < nst; i += 256) recs[i] = rec2[e0 + i];
    __syncthreads();
    int slot = t >> 2, q = t & 3;
    int node = k * BSZ + slot;
    float4 r = make_float4(0.f, 0.f, 0.f, 0.f);
    if (node < NN) {
        int a = row_ptr[node] - e0;
        int b = row_ptr[node + 1] - e0;
        float4 acc = seg_gather(recs, rec2 + e0, a, b, nst, vp2, q);
        float dv = dis[node];
        float4 self = *(const float4*)&vp2[(size_t)node * FH + q * 4];
        r.x = dv * (acc.x + self.x);
        r.y = dv * (acc.y + self.y);
        r.z = dv * (acc.z + self.z);
        r.w = dv * (acc.w + self.w);
    }
    *(float4*)&a16[slot * FH + q * 4] = r;
    __syncthreads();
    int j = t & 63;
    float bj = b2[j];
    float wreg[FH];
    #pragma unroll
    for (int kk = 0; kk < FH; ++kk) wreg[kk] = ws[kk * FOUT + j];
    for (int n = t >> 6; n < BSZ; n += 4) {
        int node2 = k * BSZ + n;
        if (node2 >= NN) break;
        const float* ar = &a16[n * FH];
        float s = 0.f;
        #pragma unroll
        for (int kk = 0; kk < FH; ++kk) s += ar[kk] * wreg[kk];
        out[(size_t)node2 * FOUT + j] = fmaxf(s + bj, 0.f);
    }
}

extern "C" void kernel_launch(void* const* d_in, const int* in_sizes, int n_in,
                              void* d_out, int out_size, void* d_ws, size_t ws_size,
                              hipStream_t stream) {
    const float* x  = (const float*)d_in[0];
    const int*   ei = (const int*)d_in[1];
    const float* W1 = (const float*)d_in[2];
    const float* b1 = (const float*)d_in[3];
    const float* W2 = (const float*)d_in[4];
    const float* b2 = (const float*)d_in[5];
    float* out = (float*)d_out;

    // workspace (~29.6 MB). rec1's 12.8MB is dead after k_sort2 and is reused
    // for vp1 (6.4MB) + vp2 (6.4MB): stream-ordered, no overlap hazard.
    char* p = (char*)d_ws;
    int*   M       = (int*)p;    p += (size_t)K * NB * 4;      // 3.2 MB
    int*   btot    = (int*)p;    p += 2048 * 4;
    int*   bstart  = (int*)p;    p += 2048 * 4;
    char*  bufA    = p;          p += (size_t)NE * 4;          // 12.8 MB (rec1 -> vp1+vp2)
    int*   rec2    = (int*)p;    p += (size_t)NE * 4;          // 12.8 MB
    int*   row_ptr = (int*)p;    p += 100032 * 4;              // 0.4 MB
    float* dis     = (float*)p;  p += 100032 * 4;              // 0.4 MB

    int*   rec1 = (int*)bufA;
    float* vp1  = (float*)bufA;
    float* vp2  = (float*)(bufA + (size_t)NN * FH * 4);

    k_cnt     <<<NB, 256, 0, stream>>>(ei, M);
    k_scanM   <<<K, 256, 0, stream>>>(M, btot);
    k_scanB   <<<1, 1024, 0, stream>>>(btot, bstart);
    k_scatter2<<<NB, 256, 0, stream>>>(ei, M, bstart, rec1);
    k_sort2   <<<K, 256, 0, stream>>>(rec1, bstart, rec2, row_ptr, dis);

    k_gemm1   <<<G1B, G1T, 0, stream>>>(x, W1, dis, vp1);
    k_agg1    <<<K, 256, 0, stream>>>(rec2, bstart, row_ptr, dis, vp1, b1, vp2);
    k_agg2    <<<K, 256, 0, stream>>>(rec2, bstart, row_ptr, dis, vp2, W2, b2, out);
}